// Round 1
// baseline (8747.073 us; speedup 1.0000x reference)
//
#include <hip/hip_runtime.h>
#include <math.h>

#define NB   2
#define SEQ  1024
#define TOK  2048      // NB*SEQ
#define DEM  1024
#define NH   16
#define DH   64
#define FFD  4096
#define NL   6
#define VOC  32000

// ---------------------------------------------------------------------------
// Embedding + positional encoding: x[t,i] = emb[ids[t],i]*32 + pe(s,i)
// pe quirk: angle = s / 10000^(2i/d); even i -> sin, odd i -> cos (same angle)
// ---------------------------------------------------------------------------
__global__ __launch_bounds__(256) void k_embed(const int* __restrict__ ids,
    const float* __restrict__ emb, float* __restrict__ x)
{
  int t = blockIdx.x;            // token 0..2047
  int s = t & (SEQ - 1);
  int id = ids[t];
  int d0 = threadIdx.x * 4;
  const float ln10000 = 9.210340371976184f;
  #pragma unroll
  for (int j = 0; j < 4; j++) {
    int i = d0 + j;
    float inv = expf(-(2.0f * (float)i / (float)DEM) * ln10000);
    float ang = (float)s * inv;
    float pe = ((i & 1) == 0) ? sinf(ang) : cosf(ang);
    x[(size_t)t * DEM + i] = emb[(size_t)id * DEM + i] * 32.0f + pe;
  }
}

// ---------------------------------------------------------------------------
// Per-head projection: out[t, h*64+e] = sum_d in[t, h*64+d] * W[d,e]
// W is [64,64] shared across heads. grid = (TOK/64, NH), 256 threads.
// ---------------------------------------------------------------------------
__global__ __launch_bounds__(256) void k_proj(const float* __restrict__ in,
    const float* __restrict__ W, float* __restrict__ out)
{
  __shared__ float Ws[64][64];
  __shared__ float xs[64][68];   // transposed [d][token], pad 68 for banks+align
  int t0 = blockIdx.x * 64;
  int h  = blockIdx.y;
  int tid = threadIdx.x;
  #pragma unroll
  for (int i = 0; i < 16; i++) {
    int idx = tid + i * 256;     // 0..4095
    int r = idx >> 6, c = idx & 63;
    Ws[r][c] = W[idx];
    xs[c][r] = in[(size_t)(t0 + r) * DEM + h * DH + c];
  }
  __syncthreads();
  int e = tid & 63, tq = tid >> 6;   // e: out col, tq: token quarter
  float acc[16] = {0.f};
  for (int d = 0; d < 64; d++) {
    float w = Ws[d][e];
    float4 x0 = *(float4*)&xs[d][tq * 16 + 0];
    float4 x1 = *(float4*)&xs[d][tq * 16 + 4];
    float4 x2 = *(float4*)&xs[d][tq * 16 + 8];
    float4 x3 = *(float4*)&xs[d][tq * 16 + 12];
    acc[0]  += x0.x * w; acc[1]  += x0.y * w; acc[2]  += x0.z * w; acc[3]  += x0.w * w;
    acc[4]  += x1.x * w; acc[5]  += x1.y * w; acc[6]  += x1.z * w; acc[7]  += x1.w * w;
    acc[8]  += x2.x * w; acc[9]  += x2.y * w; acc[10] += x2.z * w; acc[11] += x2.w * w;
    acc[12] += x3.x * w; acc[13] += x3.y * w; acc[14] += x3.z * w; acc[15] += x3.w * w;
  }
  #pragma unroll
  for (int i = 0; i < 16; i++)
    out[(size_t)(t0 + tq * 16 + i) * DEM + h * DH + e] = acc[i];
}

// ---------------------------------------------------------------------------
// Fused attention, flash-style online softmax. One block per (qtile,h,b).
// Quirk: causal-masked scores are 1e-19 (NOT -inf) -> masked keys still get
// weight exp(1e-19 - m)/Z and multiply V. So all 16 key tiles are processed.
// Thread (rg=tid/16, cg=tid%16): 4 q-rows x (4 keys | 4 dims) register tile.
// ---------------------------------------------------------------------------
__global__ __launch_bounds__(256) void k_attn(const float* __restrict__ q,
    const float* __restrict__ k, const float* __restrict__ v,
    float* __restrict__ out, int causal)
{
  __shared__ float qs[64][68];
  __shared__ float ks[64][68];
  __shared__ float vs[64][68];
  __shared__ float ps[64][68];
  int qt = blockIdx.x, h = blockIdx.y, b = blockIdx.z;
  int tid = threadIdx.x;
  int q0 = qt * 64;
  const float* qb = q + (size_t)b * SEQ * DEM + h * DH;
  const float* kb = k + (size_t)b * SEQ * DEM + h * DH;
  const float* vb = v + (size_t)b * SEQ * DEM + h * DH;
  #pragma unroll
  for (int i = 0; i < 16; i++) {
    int idx = tid + i * 256;
    int r = idx >> 6, c = idx & 63;
    qs[r][c] = qb[(size_t)(q0 + r) * DEM + c];
  }
  int rg = tid >> 4, cg = tid & 15;
  float m[4], l[4] = {0.f, 0.f, 0.f, 0.f};
  m[0] = m[1] = m[2] = m[3] = -INFINITY;
  float o[4][4] = {};

  for (int kt = 0; kt < 16; kt++) {
    __syncthreads();                      // protect ks/vs/ps from prev tile
    #pragma unroll
    for (int i = 0; i < 16; i++) {
      int idx = tid + i * 256;
      int r = idx >> 6, c = idx & 63;
      ks[r][c] = kb[(size_t)(kt * 64 + r) * DEM + c];
      vs[r][c] = vb[(size_t)(kt * 64 + r) * DEM + c];
    }
    __syncthreads();
    // ---- scores: s[i][j] = q[row rg*4+i] . k[key cg*4+j]
    float s[4][4] = {};
    for (int d4 = 0; d4 < 16; d4++) {
      float4 qv[4], kv[4];
      #pragma unroll
      for (int i = 0; i < 4; i++) qv[i] = *(float4*)&qs[rg * 4 + i][d4 * 4];
      #pragma unroll
      for (int j = 0; j < 4; j++) kv[j] = *(float4*)&ks[cg * 4 + j][d4 * 4];
      #pragma unroll
      for (int i = 0; i < 4; i++)
        #pragma unroll
        for (int j = 0; j < 4; j++)
          s[i][j] += qv[i].x * kv[j].x + qv[i].y * kv[j].y
                   + qv[i].z * kv[j].z + qv[i].w * kv[j].w;
    }
    #pragma unroll
    for (int i = 0; i < 4; i++) {
      int qi = q0 + rg * 4 + i;
      #pragma unroll
      for (int j = 0; j < 4; j++) {
        int ki = kt * 64 + cg * 4 + j;
        float sv = s[i][j] * 0.125f;          // / sqrt(64)
        if (causal && ki > qi) sv = 1e-19f;   // faithful mask quirk
        s[i][j] = sv;
      }
    }
    // ---- online softmax per q-row (reduce across the 16 cg lanes)
    #pragma unroll
    for (int i = 0; i < 4; i++) {
      float tmax = fmaxf(fmaxf(s[i][0], s[i][1]), fmaxf(s[i][2], s[i][3]));
      tmax = fmaxf(tmax, __shfl_xor(tmax, 1));
      tmax = fmaxf(tmax, __shfl_xor(tmax, 2));
      tmax = fmaxf(tmax, __shfl_xor(tmax, 4));
      tmax = fmaxf(tmax, __shfl_xor(tmax, 8));
      float mnew = fmaxf(m[i], tmax);
      float alpha = __expf(m[i] - mnew);      // m=-inf first tile -> alpha=0
      float p0 = __expf(s[i][0] - mnew), p1 = __expf(s[i][1] - mnew);
      float p2 = __expf(s[i][2] - mnew), p3 = __expf(s[i][3] - mnew);
      float rs = p0 + p1 + p2 + p3;
      rs += __shfl_xor(rs, 1); rs += __shfl_xor(rs, 2);
      rs += __shfl_xor(rs, 4); rs += __shfl_xor(rs, 8);
      l[i] = l[i] * alpha + rs;
      m[i] = mnew;
      #pragma unroll
      for (int j = 0; j < 4; j++) o[i][j] *= alpha;
      float4 pv = make_float4(p0, p1, p2, p3);
      *(float4*)&ps[rg * 4 + i][cg * 4] = pv;
    }
    __syncthreads();
    // ---- PV: o[i][di] += sum_j ps[row][j] * vs[j][cg*4+di]
    for (int j4 = 0; j4 < 16; j4++) {
      float prr[4][4];
      #pragma unroll
      for (int i = 0; i < 4; i++) {
        float4 t = *(float4*)&ps[rg * 4 + i][j4 * 4];
        prr[i][0] = t.x; prr[i][1] = t.y; prr[i][2] = t.z; prr[i][3] = t.w;
      }
      #pragma unroll
      for (int jj = 0; jj < 4; jj++) {
        float4 vv = *(float4*)&vs[j4 * 4 + jj][cg * 4];
        #pragma unroll
        for (int i = 0; i < 4; i++) {
          o[i][0] += prr[i][jj] * vv.x;
          o[i][1] += prr[i][jj] * vv.y;
          o[i][2] += prr[i][jj] * vv.z;
          o[i][3] += prr[i][jj] * vv.w;
        }
      }
    }
  }
  #pragma unroll
  for (int i = 0; i < 4; i++) {
    float inv = 1.0f / l[i];
    float4 ov = make_float4(o[i][0] * inv, o[i][1] * inv, o[i][2] * inv, o[i][3] * inv);
    size_t row = (size_t)(b * SEQ + q0 + rg * 4 + i);
    *(float4*)&out[row * DEM + h * DH + cg * 4] = ov;
  }
}

// ---------------------------------------------------------------------------
// out = LayerNorm(a + r) * g + bb   (biased variance, eps 1e-5)
// one block per token; in-place on r is safe (each elem read+written by owner)
// ---------------------------------------------------------------------------
__global__ __launch_bounds__(256) void k_addln(const float* __restrict__ a,
    const float* __restrict__ r, const float* __restrict__ g,
    const float* __restrict__ bb, float* __restrict__ out)
{
  int t = blockIdx.x, tid = threadIdx.x;
  size_t base = (size_t)t * DEM + tid * 4;
  float4 av = *(const float4*)&a[base];
  float4 rv = *(const float4*)&r[base];
  float x0 = av.x + rv.x, x1 = av.y + rv.y, x2 = av.z + rv.z, x3 = av.w + rv.w;
  float s = x0 + x1 + x2 + x3;
  float qq = x0 * x0 + x1 * x1 + x2 * x2 + x3 * x3;
  #pragma unroll
  for (int msk = 32; msk; msk >>= 1) {
    s  += __shfl_xor(s, msk);
    qq += __shfl_xor(qq, msk);
  }
  __shared__ float red[8];
  if ((tid & 63) == 0) { red[tid >> 6] = s; red[4 + (tid >> 6)] = qq; }
  __syncthreads();
  s  = red[0] + red[1] + red[2] + red[3];
  qq = red[4] + red[5] + red[6] + red[7];
  float mu = s * (1.0f / DEM);
  float var = qq * (1.0f / DEM) - mu * mu;
  float rstd = rsqrtf(var + 1e-5f);
  float4 gv = *(const float4*)&g[tid * 4];
  float4 bv = *(const float4*)&bb[tid * 4];
  float4 ov;
  ov.x = (x0 - mu) * rstd * gv.x + bv.x;
  ov.y = (x1 - mu) * rstd * gv.y + bv.y;
  ov.z = (x2 - mu) * rstd * gv.z + bv.z;
  ov.w = (x3 - mu) * rstd * gv.w + bv.w;
  *(float4*)&out[base] = ov;
}

// ---------------------------------------------------------------------------
// fp32 tiled GEMM: C[M,N] = A[M,K] @ W[K,N] + bias[N], optional relu.
// 128x128 tile, BK=16, 256 threads, 8x8 per thread. All dims divide tiles.
// ---------------------------------------------------------------------------
__global__ __launch_bounds__(256) void k_gemm(const float* __restrict__ A,
    const float* __restrict__ Bw, const float* __restrict__ bias,
    float* __restrict__ C, int M, int N, int K, int relu)
{
  __shared__ float As[16][132];   // transposed A tile [k][m], pad for b128
  __shared__ float Bs[16][132];   // [k][n]
  int bn = blockIdx.x, bm = blockIdx.y;
  int tid = threadIdx.x;
  int tx = tid & 15, ty = tid >> 4;
  const float* Ablk = A + (size_t)bm * 128 * K;
  const float* Bblk = Bw + (size_t)bn * 128;
  float acc[8][8] = {};
  for (int kt = 0; kt < K; kt += 16) {
    #pragma unroll
    for (int i = 0; i < 2; i++) {          // A: 128x16 as 512 float4
      int idx = tid + i * 256;
      int r = idx >> 2, c4 = (idx & 3) * 4;
      float4 av = *(const float4*)&Ablk[(size_t)r * K + kt + c4];
      As[c4 + 0][r] = av.x; As[c4 + 1][r] = av.y;
      As[c4 + 2][r] = av.z; As[c4 + 3][r] = av.w;
    }
    #pragma unroll
    for (int i = 0; i < 2; i++) {          // B: 16x128 as 512 float4
      int idx = tid + i * 256;
      int r = idx >> 5, c4 = (idx & 31) * 4;
      *(float4*)&Bs[r][c4] = *(const float4*)&Bblk[(size_t)(kt + r) * N + c4];
    }
    __syncthreads();
    #pragma unroll
    for (int kk = 0; kk < 16; kk++) {
      float a[8], b[8];
      *(float4*)&a[0] = *(float4*)&As[kk][ty * 8];
      *(float4*)&a[4] = *(float4*)&As[kk][ty * 8 + 4];
      *(float4*)&b[0] = *(float4*)&Bs[kk][tx * 8];
      *(float4*)&b[4] = *(float4*)&Bs[kk][tx * 8 + 4];
      #pragma unroll
      for (int i = 0; i < 8; i++)
        #pragma unroll
        for (int j = 0; j < 8; j++)
          acc[i][j] = fmaf(a[i], b[j], acc[i][j]);
    }
    __syncthreads();
  }
  #pragma unroll
  for (int i = 0; i < 8; i++) {
    size_t row = (size_t)bm * 128 + ty * 8 + i;
    int col = bn * 128 + tx * 8;
    float4 v0, v1;
    float* o0 = (float*)&v0; float* o1 = (float*)&v1;
    #pragma unroll
    for (int j = 0; j < 4; j++) {
      float u0 = acc[i][j]     + bias[col + j];
      float u1 = acc[i][4 + j] + bias[col + 4 + j];
      if (relu) { u0 = fmaxf(u0, 0.f); u1 = fmaxf(u1, 0.f); }
      o0[j] = u0; o1[j] = u1;
    }
    *(float4*)&C[row * N + col]     = v0;
    *(float4*)&C[row * N + col + 4] = v1;
  }
}

// ---------------------------------------------------------------------------
extern "C" void kernel_launch(void* const* d_in, const int* in_sizes, int n_in,
                              void* d_out, int out_size, void* d_ws, size_t ws_size,
                              hipStream_t stream) {
  const int*   ids   = (const int*)  d_in[0];
  const float* enc_k = (const float*)d_in[1];
  const float* enc_v = (const float*)d_in[2];
  const float* emb   = (const float*)d_in[3];
  const float* Wq_m  = (const float*)d_in[4];
  const float* Wk_m  = (const float*)d_in[5];
  const float* Wv_m  = (const float*)d_in[6];
  const float* Wq_c  = (const float*)d_in[7];
  const float* Wk_c  = (const float*)d_in[8];
  const float* Wv_c  = (const float*)d_in[9];
  const float* ln1_g = (const float*)d_in[10];
  const float* ln1_b = (const float*)d_in[11];
  const float* ln2_g = (const float*)d_in[12];
  const float* ln2_b = (const float*)d_in[13];
  const float* ln3_g = (const float*)d_in[14];
  const float* ln3_b = (const float*)d_in[15];
  const float* W1    = (const float*)d_in[16];
  const float* b1    = (const float*)d_in[17];
  const float* W2    = (const float*)d_in[18];
  const float* b2    = (const float*)d_in[19];
  const float* Wout  = (const float*)d_in[20];
  const float* bout  = (const float*)d_in[21];
  float* out = (float*)d_out;

  // workspace layout (floats). ff aliases qb..(qb+4*TD): attention buffers and
  // the FFN intermediate are never live simultaneously. Total = 7*TD = 58.7MB.
  const size_t TD = (size_t)TOK * DEM;   // 2M floats
  float* ws = (float*)d_ws;
  float* x  = ws;
  float* h  = ws + TD;
  float* op = ws + 2 * TD;
  float* qb = ws + 3 * TD;
  float* kb = ws + 4 * TD;
  float* vb = ws + 5 * TD;
  float* ff = qb;                        // needs 4*TD, overlaps qb/kb/vb + spare

  dim3 blk(256);
  dim3 gproj(TOK / 64, NH);
  dim3 gattn(SEQ / 64, NH, NB);

  k_embed<<<TOK, blk, 0, stream>>>(ids, emb, x);

  for (int l = 0; l < NL; l++) {
    const size_t wofs = (size_t)l * DH * DH;      // 4096 per layer
    const size_t lofs = (size_t)l * DEM;
    // ---- masked self-attention
    k_proj<<<gproj, blk, 0, stream>>>(x, Wq_m + wofs, qb);
    k_proj<<<gproj, blk, 0, stream>>>(x, Wk_m + wofs, kb);
    k_proj<<<gproj, blk, 0, stream>>>(x, Wv_m + wofs, vb);
    k_attn<<<gattn, blk, 0, stream>>>(qb, kb, vb, op, 1);
    k_addln<<<TOK, blk, 0, stream>>>(op, x, ln1_g + lofs, ln1_b + lofs, h);
    // ---- cross-attention (q from h, k/v from encoder)
    k_proj<<<gproj, blk, 0, stream>>>(h,     Wq_c + wofs, qb);
    k_proj<<<gproj, blk, 0, stream>>>(enc_k, Wk_c + wofs, kb);
    k_proj<<<gproj, blk, 0, stream>>>(enc_v, Wv_c + wofs, vb);
    k_attn<<<gattn, blk, 0, stream>>>(qb, kb, vb, op, 0);
    k_addln<<<TOK, blk, 0, stream>>>(op, h, ln2_g + lofs, ln2_b + lofs, h);
    // ---- FFN
    k_gemm<<<dim3(FFD / 128, TOK / 128), blk, 0, stream>>>(
        h, W1 + (size_t)l * DEM * FFD, b1 + (size_t)l * FFD, ff,
        TOK, FFD, DEM, 1);
    k_gemm<<<dim3(DEM / 128, TOK / 128), blk, 0, stream>>>(
        ff, W2 + (size_t)l * FFD * DEM, b2 + lofs, op,
        TOK, DEM, FFD, 0);
    k_addln<<<TOK, blk, 0, stream>>>(op, h, ln3_g + lofs, ln3_b + lofs, x);
  }
  // ---- output projection
  k_gemm<<<dim3(VOC / 128, TOK / 128), blk, 0, stream>>>(
      x, Wout, bout, out, TOK, VOC, DEM, 0);
}

// Round 2
// 4129.476 us; speedup vs baseline: 2.1182x; 2.1182x over previous
//
#include <hip/hip_runtime.h>
#include <math.h>

#define NB   2
#define SEQ  1024
#define TOK  2048      // NB*SEQ
#define DEM  1024
#define NH   16
#define DH   64
#define FFD  4096
#define NL   6
#define VOC  32000

typedef __bf16 bf16x8 __attribute__((ext_vector_type(8)));
typedef float  f32x4  __attribute__((ext_vector_type(4)));
typedef const __attribute__((address_space(1))) void gvoid_t;
typedef __attribute__((address_space(3)))       void lvoid_t;

// ---------------------------------------------------------------------------
// Embedding + positional encoding: x[t,i] = emb[ids[t],i]*32 + pe(s,i)
// ---------------------------------------------------------------------------
__global__ __launch_bounds__(256) void k_embed(const int* __restrict__ ids,
    const float* __restrict__ emb, float* __restrict__ x)
{
  int t = blockIdx.x;
  int s = t & (SEQ - 1);
  int id = ids[t];
  int d0 = threadIdx.x * 4;
  const float ln10000 = 9.210340371976184f;
  #pragma unroll
  for (int j = 0; j < 4; j++) {
    int i = d0 + j;
    float inv = expf(-(2.0f * (float)i / (float)DEM) * ln10000);
    float ang = (float)s * inv;
    float pe = ((i & 1) == 0) ? sinf(ang) : cosf(ang);
    x[(size_t)t * DEM + i] = emb[(size_t)id * DEM + i] * 32.0f + pe;
  }
}

// ---------------------------------------------------------------------------
// Fused q/k/v per-head projection (3 phases through shared LDS, 1 dispatch).
// out[t, h*64+e] = sum_d in[t, h*64+d] * W[d,e]; grid (TOK/64, NH)
// ---------------------------------------------------------------------------
__global__ __launch_bounds__(256) void k_proj3(
    const float* __restrict__ qi, const float* __restrict__ ki,
    const float* __restrict__ vi,
    const float* __restrict__ Wq, const float* __restrict__ Wk,
    const float* __restrict__ Wv,
    float* __restrict__ qo, float* __restrict__ ko, float* __restrict__ vo)
{
  __shared__ float Ws[64][64];
  __shared__ float xs[64][68];
  int t0 = blockIdx.x * 64, hh = blockIdx.y, tid = threadIdx.x;
  const float* ins[3]  = {qi, ki, vi};
  const float* Wp[3]   = {Wq, Wk, Wv};
  float*       outs[3] = {qo, ko, vo};
  #pragma unroll 1
  for (int p = 0; p < 3; p++) {
    if (p) __syncthreads();
    #pragma unroll
    for (int i = 0; i < 16; i++) {
      int idx = tid + i * 256;
      int r = idx >> 6, c = idx & 63;
      Ws[r][c] = Wp[p][idx];
      xs[c][r] = ins[p][(size_t)(t0 + r) * DEM + hh * DH + c];
    }
    __syncthreads();
    int e = tid & 63, tq = tid >> 6;
    float acc[16] = {0.f};
    for (int d = 0; d < 64; d++) {
      float w = Ws[d][e];
      float4 x0 = *(float4*)&xs[d][tq * 16 + 0];
      float4 x1 = *(float4*)&xs[d][tq * 16 + 4];
      float4 x2 = *(float4*)&xs[d][tq * 16 + 8];
      float4 x3 = *(float4*)&xs[d][tq * 16 + 12];
      acc[0]  += x0.x * w; acc[1]  += x0.y * w; acc[2]  += x0.z * w; acc[3]  += x0.w * w;
      acc[4]  += x1.x * w; acc[5]  += x1.y * w; acc[6]  += x1.z * w; acc[7]  += x1.w * w;
      acc[8]  += x2.x * w; acc[9]  += x2.y * w; acc[10] += x2.z * w; acc[11] += x2.w * w;
      acc[12] += x3.x * w; acc[13] += x3.y * w; acc[14] += x3.z * w; acc[15] += x3.w * w;
    }
    #pragma unroll
    for (int i = 0; i < 16; i++)
      outs[p][(size_t)(t0 + tq * 16 + i) * DEM + hh * DH + e] = acc[i];
  }
}

// ---------------------------------------------------------------------------
// Fused attention, flash-style online softmax (fp32). Quirk: masked scores
// are 1e-19 (NOT -inf), so all key tiles are processed even when causal.
// ---------------------------------------------------------------------------
__global__ __launch_bounds__(256) void k_attn(const float* __restrict__ q,
    const float* __restrict__ k, const float* __restrict__ v,
    float* __restrict__ out, int causal)
{
  __shared__ float qs[64][68];
  __shared__ float ks[64][68];
  __shared__ float vs[64][68];
  __shared__ float ps[64][68];
  int qt = blockIdx.x, h = blockIdx.y, b = blockIdx.z;
  int tid = threadIdx.x;
  int q0 = qt * 64;
  const float* qb = q + (size_t)b * SEQ * DEM + h * DH;
  const float* kb = k + (size_t)b * SEQ * DEM + h * DH;
  const float* vb = v + (size_t)b * SEQ * DEM + h * DH;
  #pragma unroll
  for (int i = 0; i < 16; i++) {
    int idx = tid + i * 256;
    int r = idx >> 6, c = idx & 63;
    qs[r][c] = qb[(size_t)(q0 + r) * DEM + c];
  }
  int rg = tid >> 4, cg = tid & 15;
  float m[4], l[4] = {0.f, 0.f, 0.f, 0.f};
  m[0] = m[1] = m[2] = m[3] = -INFINITY;
  float o[4][4] = {};

  for (int kt = 0; kt < 16; kt++) {
    __syncthreads();
    #pragma unroll
    for (int i = 0; i < 16; i++) {
      int idx = tid + i * 256;
      int r = idx >> 6, c = idx & 63;
      ks[r][c] = kb[(size_t)(kt * 64 + r) * DEM + c];
      vs[r][c] = vb[(size_t)(kt * 64 + r) * DEM + c];
    }
    __syncthreads();
    float s[4][4] = {};
    for (int d4 = 0; d4 < 16; d4++) {
      float4 qv[4], kv[4];
      #pragma unroll
      for (int i = 0; i < 4; i++) qv[i] = *(float4*)&qs[rg * 4 + i][d4 * 4];
      #pragma unroll
      for (int j = 0; j < 4; j++) kv[j] = *(float4*)&ks[cg * 4 + j][d4 * 4];
      #pragma unroll
      for (int i = 0; i < 4; i++)
        #pragma unroll
        for (int j = 0; j < 4; j++)
          s[i][j] += qv[i].x * kv[j].x + qv[i].y * kv[j].y
                   + qv[i].z * kv[j].z + qv[i].w * kv[j].w;
    }
    #pragma unroll
    for (int i = 0; i < 4; i++) {
      int qi = q0 + rg * 4 + i;
      #pragma unroll
      for (int j = 0; j < 4; j++) {
        int ki = kt * 64 + cg * 4 + j;
        float sv = s[i][j] * 0.125f;
        if (causal && ki > qi) sv = 1e-19f;
        s[i][j] = sv;
      }
    }
    #pragma unroll
    for (int i = 0; i < 4; i++) {
      float tmax = fmaxf(fmaxf(s[i][0], s[i][1]), fmaxf(s[i][2], s[i][3]));
      tmax = fmaxf(tmax, __shfl_xor(tmax, 1));
      tmax = fmaxf(tmax, __shfl_xor(tmax, 2));
      tmax = fmaxf(tmax, __shfl_xor(tmax, 4));
      tmax = fmaxf(tmax, __shfl_xor(tmax, 8));
      float mnew = fmaxf(m[i], tmax);
      float alpha = __expf(m[i] - mnew);
      float p0 = __expf(s[i][0] - mnew), p1 = __expf(s[i][1] - mnew);
      float p2 = __expf(s[i][2] - mnew), p3 = __expf(s[i][3] - mnew);
      float rs = p0 + p1 + p2 + p3;
      rs += __shfl_xor(rs, 1); rs += __shfl_xor(rs, 2);
      rs += __shfl_xor(rs, 4); rs += __shfl_xor(rs, 8);
      l[i] = l[i] * alpha + rs;
      m[i] = mnew;
      #pragma unroll
      for (int j = 0; j < 4; j++) o[i][j] *= alpha;
      float4 pv = make_float4(p0, p1, p2, p3);
      *(float4*)&ps[rg * 4 + i][cg * 4] = pv;
    }
    __syncthreads();
    for (int j4 = 0; j4 < 16; j4++) {
      float prr[4][4];
      #pragma unroll
      for (int i = 0; i < 4; i++) {
        float4 t = *(float4*)&ps[rg * 4 + i][j4 * 4];
        prr[i][0] = t.x; prr[i][1] = t.y; prr[i][2] = t.z; prr[i][3] = t.w;
      }
      #pragma unroll
      for (int jj = 0; jj < 4; jj++) {
        float4 vv = *(float4*)&vs[j4 * 4 + jj][cg * 4];
        #pragma unroll
        for (int i = 0; i < 4; i++) {
          o[i][0] += prr[i][jj] * vv.x;
          o[i][1] += prr[i][jj] * vv.y;
          o[i][2] += prr[i][jj] * vv.z;
          o[i][3] += prr[i][jj] * vv.w;
        }
      }
    }
  }
  #pragma unroll
  for (int i = 0; i < 4; i++) {
    float inv = 1.0f / l[i];
    float4 ov = make_float4(o[i][0] * inv, o[i][1] * inv, o[i][2] * inv, o[i][3] * inv);
    size_t row = (size_t)(b * SEQ + q0 + rg * 4 + i);
    *(float4*)&out[row * DEM + h * DH + cg * 4] = ov;
  }
}

// ---------------------------------------------------------------------------
// out = LayerNorm(a + r)*g + bb, plus optional bf16 duplicate of out.
// ---------------------------------------------------------------------------
__global__ __launch_bounds__(256) void k_addln(const float* __restrict__ a,
    const float* __restrict__ r, const float* __restrict__ g,
    const float* __restrict__ bb, float* __restrict__ out,
    __bf16* __restrict__ obf)
{
  int t = blockIdx.x, tid = threadIdx.x;
  size_t base = (size_t)t * DEM + tid * 4;
  float4 av = *(const float4*)&a[base];
  float4 rv = *(const float4*)&r[base];
  float x0 = av.x + rv.x, x1 = av.y + rv.y, x2 = av.z + rv.z, x3 = av.w + rv.w;
  float s = x0 + x1 + x2 + x3;
  float qq = x0 * x0 + x1 * x1 + x2 * x2 + x3 * x3;
  #pragma unroll
  for (int msk = 32; msk; msk >>= 1) {
    s  += __shfl_xor(s, msk);
    qq += __shfl_xor(qq, msk);
  }
  __shared__ float red[8];
  if ((tid & 63) == 0) { red[tid >> 6] = s; red[4 + (tid >> 6)] = qq; }
  __syncthreads();
  s  = red[0] + red[1] + red[2] + red[3];
  qq = red[4] + red[5] + red[6] + red[7];
  float mu = s * (1.0f / DEM);
  float var = qq * (1.0f / DEM) - mu * mu;
  float rstd = rsqrtf(var + 1e-5f);
  float4 gv = *(const float4*)&g[tid * 4];
  float4 bv = *(const float4*)&bb[tid * 4];
  float4 ov;
  ov.x = (x0 - mu) * rstd * gv.x + bv.x;
  ov.y = (x1 - mu) * rstd * gv.y + bv.y;
  ov.z = (x2 - mu) * rstd * gv.z + bv.z;
  ov.w = (x3 - mu) * rstd * gv.w + bv.w;
  *(float4*)&out[base] = ov;
  if (obf) {
    __bf16 tb[4] = {(__bf16)ov.x, (__bf16)ov.y, (__bf16)ov.z, (__bf16)ov.w};
    *(uint2*)&obf[base] = *(uint2*)tb;
  }
}

// ---------------------------------------------------------------------------
// Transpose-convert: W[K][N] fp32  ->  Wt[N][K] bf16. 64x64 tiles.
// ---------------------------------------------------------------------------
__global__ __launch_bounds__(256) void k_cvt_t(const float* __restrict__ W,
    __bf16* __restrict__ Wt, int K, int N)
{
  __shared__ float t[64][65];
  int n0 = blockIdx.x * 64, k0 = blockIdx.y * 64;
  int tid = threadIdx.x;
  int c = (tid & 15) * 4, r = tid >> 4;
  #pragma unroll
  for (int i = 0; i < 4; i++) {
    float4 v = *(const float4*)&W[(size_t)(k0 + r + i * 16) * N + n0 + c];
    t[r + i * 16][c] = v.x; t[r + i * 16][c + 1] = v.y;
    t[r + i * 16][c + 2] = v.z; t[r + i * 16][c + 3] = v.w;
  }
  __syncthreads();
  int row = tid >> 2, ko = (tid & 3) * 16;
  alignas(16) __bf16 tmp[16];
  #pragma unroll
  for (int j = 0; j < 16; j++) tmp[j] = (__bf16)t[ko + j][row];
  uint4* dst = (uint4*)&Wt[(size_t)(n0 + row) * K + k0 + ko];
  dst[0] = ((uint4*)tmp)[0];
  dst[1] = ((uint4*)tmp)[1];
}

// ---------------------------------------------------------------------------
// bf16 MFMA GEMM (m97 structure): C[M,N] = A[M,K] @ Bt[N,K]^T + bias.
// 128x128 tile, BK=32, 256 thr = 4 waves in 2x2, each wave 4x4 of 16x16x32.
// global_load_lds width 16 staging; LDS [128][32] bf16, no padding (required
// by the wave-uniform-base + lane*16 LDS addressing of global_load_lds).
// ---------------------------------------------------------------------------
template <int OUT_BF, int RELU>
__global__ __launch_bounds__(256) void k_gemm_bf(
    const __bf16* __restrict__ A, const __bf16* __restrict__ Bt,
    const float* __restrict__ bias, void* __restrict__ Cout,
    int M, int N, int K)
{
  __shared__ __bf16 As[128 * 32];
  __shared__ __bf16 Bs[128 * 32];
  int tid = threadIdx.x;
  int m0 = blockIdx.x * 128, n0 = blockIdx.y * 128;  // x=bm fastest: B-tile reuse
  const __bf16* Ab = A + (size_t)m0 * K;
  const __bf16* Bb = Bt + (size_t)n0 * K;
  int lane = tid & 63, wave = tid >> 6;
  int wm = (wave >> 1) * 64, wn = (wave & 1) * 64;
  int fr = lane & 15;           // row within 16-tile (m for A, n for B)
  int fk = (lane >> 4) * 8;     // k offset of this lane's 8 elements
  f32x4 acc[4][4] = {};

  const __bf16* Ald = As + (wm + fr) * 32 + fk;
  const __bf16* Bld = Bs + (wn + fr) * 32 + fk;

  for (int kt = 0; kt < K; kt += 32) {
    __syncthreads();
    #pragma unroll
    for (int i = 0; i < 2; i++) {
      int idx = tid + i * 256;                 // 0..511
      int row = idx >> 2, ko = (idx & 3) * 8;  // 4 lanes per 32-elem row
      __builtin_amdgcn_global_load_lds(
          (gvoid_t*)(Ab + (size_t)row * K + kt + ko),
          (lvoid_t*)(As + idx * 8), 16, 0, 0);
      __builtin_amdgcn_global_load_lds(
          (gvoid_t*)(Bb + (size_t)row * K + kt + ko),
          (lvoid_t*)(Bs + idx * 8), 16, 0, 0);
    }
    __syncthreads();
    bf16x8 af[4], bfr[4];
    #pragma unroll
    for (int i = 0; i < 4; i++) af[i]  = *(const bf16x8*)(Ald + i * 16 * 32);
    #pragma unroll
    for (int j = 0; j < 4; j++) bfr[j] = *(const bf16x8*)(Bld + j * 16 * 32);
    #pragma unroll
    for (int i = 0; i < 4; i++)
      #pragma unroll
      for (int j = 0; j < 4; j++)
        acc[i][j] = __builtin_amdgcn_mfma_f32_16x16x32_bf16(
            af[i], bfr[j], acc[i][j], 0, 0, 0);
  }
  // epilogue: C/D map col=lane&15, row=(lane>>4)*4+reg
  int orow = (lane >> 4) * 4, ocol = lane & 15;
  #pragma unroll
  for (int i = 0; i < 4; i++) {
    #pragma unroll
    for (int j = 0; j < 4; j++) {
      int col = n0 + wn + j * 16 + ocol;
      float bsv = bias[col];
      #pragma unroll
      for (int r = 0; r < 4; r++) {
        size_t row = (size_t)(m0 + wm + i * 16 + orow + r);
        float u = acc[i][j][r] + bsv;
        if (RELU) u = fmaxf(u, 0.f);
        if (OUT_BF) ((__bf16*)Cout)[row * N + col] = (__bf16)u;
        else        ((float*)Cout)[row * N + col] = u;
      }
    }
  }
}

// ---------------------------------------------------------------------------
extern "C" void kernel_launch(void* const* d_in, const int* in_sizes, int n_in,
                              void* d_out, int out_size, void* d_ws, size_t ws_size,
                              hipStream_t stream) {
  const int*   ids   = (const int*)  d_in[0];
  const float* enc_k = (const float*)d_in[1];
  const float* enc_v = (const float*)d_in[2];
  const float* emb   = (const float*)d_in[3];
  const float* Wq_m  = (const float*)d_in[4];
  const float* Wk_m  = (const float*)d_in[5];
  const float* Wv_m  = (const float*)d_in[6];
  const float* Wq_c  = (const float*)d_in[7];
  const float* Wk_c  = (const float*)d_in[8];
  const float* Wv_c  = (const float*)d_in[9];
  const float* ln1_g = (const float*)d_in[10];
  const float* ln1_b = (const float*)d_in[11];
  const float* ln2_g = (const float*)d_in[12];
  const float* ln2_b = (const float*)d_in[13];
  const float* ln3_g = (const float*)d_in[14];
  const float* ln3_b = (const float*)d_in[15];
  const float* W1    = (const float*)d_in[16];
  const float* b1    = (const float*)d_in[17];
  const float* W2    = (const float*)d_in[18];
  const float* b2    = (const float*)d_in[19];
  const float* Wout  = (const float*)d_in[20];
  const float* bout  = (const float*)d_in[21];
  float* out = (float*)d_out;

  // ws layout: 6 fp32 TD buffers | abf bf16 TD | w1t | w2t | woutt  = 136.8 MB
  const size_t TD = (size_t)TOK * DEM;
  float* ws = (float*)d_ws;
  float* x  = ws;
  float* h  = ws + TD;
  float* op = ws + 2 * TD;
  float* qb = ws + 3 * TD;
  float* kb = ws + 4 * TD;
  float* vb = ws + 5 * TD;
  __bf16* ffb   = (__bf16*)qb;                 // TOK*FFD bf16 == qb+kb exactly
  __bf16* abf   = (__bf16*)(ws + 6 * TD);      // TD bf16
  __bf16* w1t   = abf + TD;                    // FFD*DEM
  __bf16* w2t   = w1t + (size_t)FFD * DEM;     // DEM*FFD
  __bf16* woutt = w2t + (size_t)FFD * DEM;     // VOC*DEM

  dim3 blk(256);
  dim3 gproj(TOK / 64, NH);
  dim3 gattn(SEQ / 64, NH, NB);

  k_embed<<<TOK, blk, 0, stream>>>(ids, emb, x);
  // convert Wout once per call (independent of the layer loop)
  k_cvt_t<<<dim3(VOC / 64, DEM / 64), blk, 0, stream>>>(Wout, woutt, DEM, VOC);

  for (int l = 0; l < NL; l++) {
    const size_t wofs = (size_t)l * DH * DH;
    const size_t lofs = (size_t)l * DEM;
    // ---- masked self-attention
    k_proj3<<<gproj, blk, 0, stream>>>(x, x, x,
        Wq_m + wofs, Wk_m + wofs, Wv_m + wofs, qb, kb, vb);
    k_attn<<<gattn, blk, 0, stream>>>(qb, kb, vb, op, 1);
    k_addln<<<TOK, blk, 0, stream>>>(op, x, ln1_g + lofs, ln1_b + lofs, h, nullptr);
    // ---- cross-attention
    k_proj3<<<gproj, blk, 0, stream>>>(h, enc_k, enc_v,
        Wq_c + wofs, Wk_c + wofs, Wv_c + wofs, qb, kb, vb);
    k_attn<<<gattn, blk, 0, stream>>>(qb, kb, vb, op, 0);
    k_addln<<<TOK, blk, 0, stream>>>(op, h, ln2_g + lofs, ln2_b + lofs, h, abf);
    // ---- FFN (bf16 MFMA)
    k_cvt_t<<<dim3(FFD / 64, DEM / 64), blk, 0, stream>>>(
        W1 + (size_t)l * DEM * FFD, w1t, DEM, FFD);
    k_cvt_t<<<dim3(DEM / 64, FFD / 64), blk, 0, stream>>>(
        W2 + (size_t)l * FFD * DEM, w2t, FFD, DEM);
    k_gemm_bf<1, 1><<<dim3(TOK / 128, FFD / 128), blk, 0, stream>>>(
        abf, w1t, b1 + (size_t)l * FFD, (void*)ffb, TOK, FFD, DEM);
    k_gemm_bf<0, 0><<<dim3(TOK / 128, DEM / 128), blk, 0, stream>>>(
        ffb, w2t, b2 + lofs, (void*)op, TOK, DEM, FFD);
    k_addln<<<TOK, blk, 0, stream>>>(op, h, ln3_g + lofs, ln3_b + lofs, x, abf);
  }
  // ---- output projection (A = abf from last ln3)
  k_gemm_bf<0, 0><<<dim3(TOK / 128, VOC / 128), blk, 0, stream>>>(
      abf, woutt, bout, (void*)out, TOK, VOC, DEM);
}